// Round 10
// baseline (134.771 us; speedup 1.0000x reference)
//
#include <hip/hip_runtime.h>
#include <hip/hip_bf16.h>

// out[b,co,h,w] = in[b,co,h,w] + sum_{ci,kh,kw} in[b,ci,h+kh-1,w+kw-1] * W[b,co,ci,kh,kw]
// B=16, C=128, H=W=64, K=3, pad=1, fp32 in/out.
// fp16 implicit GEMM on mfma_f32_32x32x16_f16.
// R10: SINGLE-STAGE — whole 3-row X working set (50.7 KB fp16) staged to LDS once,
// ONE barrier, then 72 barrier-free K-steps. W fragments from global wp (L2-hot).

typedef _Float16 h8 __attribute__((ext_vector_type(8)));
typedef float f32x16 __attribute__((ext_vector_type(16)));
typedef float f4 __attribute__((ext_vector_type(4)));

#define MFMA32 __builtin_amdgcn_mfma_f32_32x32x16_f16

// ---------------- W prepass: W[b][co][ci][kh][kw] fp32 -> wp[b][kh][kc][kwoct12][co128][ci8] fp16 ----
__global__ __launch_bounds__(256) void w_prepass(const float* __restrict__ W,
                                                 _Float16* __restrict__ wp) {
    __shared__ float raw[8 * 1153];
    const int bid = blockIdx.x;           // 256 = b16 * cog16
    const int b   = bid >> 4;
    const int co0 = (bid & 15) * 8;
    const int t   = threadIdx.x;

    const float* src = W + (size_t)(b * 128 + co0) * 1152;
#pragma unroll
    for (int i = 0; i < 9; ++i) {
        int idx  = (i * 256 + t) * 4;
        f4 v     = *(const f4*)(src + idx);
        int co_l = idx / 1152;
        int rem  = idx - co_l * 1152;
        *(f4*)&raw[co_l * 1153 + rem] = v;
    }
    __syncthreads();

#pragma unroll
    for (int i = 0; i < 9; ++i) {
        int c    = i * 256 + t;
        int jh   = c & 1;
        int co_l = (c >> 1) & 7;
        int oct  = (c >> 4) & 3;
        int r    = c >> 6;                // 0..35 = (kh*4+kc)*3 + kw
        int kw   = r % 3;
        int r2   = r / 3;
        int kc   = r2 & 3;
        int kh   = r2 >> 2;
        int cib  = kc * 32 + oct * 8 + jh * 4;
        _Float16 v0 = (_Float16)raw[co_l * 1153 + (cib + 0) * 9 + kh * 3 + kw];
        _Float16 v1 = (_Float16)raw[co_l * 1153 + (cib + 1) * 9 + kh * 3 + kw];
        _Float16 v2 = (_Float16)raw[co_l * 1153 + (cib + 2) * 9 + kh * 3 + kw];
        _Float16 v3 = (_Float16)raw[co_l * 1153 + (cib + 3) * 9 + kh * 3 + kw];
        size_t o = ((size_t)(b * 3 + kh) * 4 + kc) * 12288 +
                   (size_t)(kw * 4 + oct) * 1024 + (size_t)(co0 + co_l) * 8 + jh * 4;
        wp[o + 0] = v0; wp[o + 1] = v1; wp[o + 2] = v2; wp[o + 3] = v3;
    }
}

// ---------------- main kernel ----------------
// grid 1024 = 16 b * 64 rows (XCD-swizzled); 256 thr = 4 waves.
// Wave wv: co tile [wv*32, wv*32+32), px 0..63 -> 2 MFMA tiles/ks, acc 32 regs.
// LDS: sX[3y][16oct][66x'][8ci] fp16 = 50688 B, staged ONCE. 72 K-steps, no main-loop barrier.
// A-operand: global h8 loads from wp (coalesced 512B segments/half-wave; L2-hot).

__global__ __launch_bounds__(256, 3) void conv_main(const float* __restrict__ X,
                                                    const _Float16* __restrict__ wp,
                                                    float* __restrict__ out) {
    __shared__ _Float16 sX[3 * 16 * 66 * 8];   // 50688 B

    const int t    = threadIdx.x;
    const int lane = t & 63;
    const int l31  = lane & 31;
    const int lhi  = lane >> 5;
    const int wv   = t >> 6;

    // XCD swizzle: 1024 % 8 == 0 -> bijective; adjacent h land on same XCD (X-row L2 reuse)
    const int bid   = blockIdx.x;
    const int swz   = (bid & 7) * 128 + (bid >> 3);
    const int batch = swz >> 6;
    const int h     = swz & 63;

    f32x16 acc[2];
#pragma unroll
    for (int nt = 0; nt < 2; ++nt)
#pragma unroll
        for (int r = 0; r < 16; ++r) acc[nt][r] = 0.f;

    // ---- halo zeros: x'=0 and x'=65 for all 48 (y,oct) rows ----
    if (t < 96) {
        int y = t >> 5, oct = (t >> 1) & 15, side = t & 1;
        h8 z = {};
        *(h8*)&sX[((y * 16 + oct) * 66 + side * 65) * 8] = z;
    }

    // ---- stage all 3 y-rows x 128 ci x 64 px, once ----
    {
        const int o  = t >> 4;         // ci octet 0..15
        const int xq = (t & 15) * 4;   // x base
#pragma unroll
        for (int y = 0; y < 3; ++y) {
            const int yy = h + y - 1;
            f4 xr[8];
            if (yy >= 0 && yy < 64) {
                const float* xp = X + ((size_t)(batch * 128 + o * 8) * 64 + yy) * 64 + xq;
#pragma unroll
                for (int j = 0; j < 8; ++j) xr[j] = *(const f4*)(xp + (size_t)j * 4096);
            } else {
#pragma unroll
                for (int j = 0; j < 8; ++j) xr[j] = (f4){0.f, 0.f, 0.f, 0.f};
            }
#pragma unroll
            for (int k = 0; k < 4; ++k) {
                h8 v = {(_Float16)xr[0][k], (_Float16)xr[1][k],
                        (_Float16)xr[2][k], (_Float16)xr[3][k],
                        (_Float16)xr[4][k], (_Float16)xr[5][k],
                        (_Float16)xr[6][k], (_Float16)xr[7][k]};
                *(h8*)&sX[((y * 16 + o) * 66 + xq + 1 + k) * 8] = v;
            }
        }
    }
    __syncthreads();   // the ONLY barrier

    // ---- 72 K-steps, barrier-free ----
    const int wrow = (lhi * 128 + wv * 32 + l31) * 8;   // af per-thread offset
#pragma unroll 1
    for (int kh = 0; kh < 3; ++kh) {
#pragma unroll 1
        for (int kc = 0; kc < 4; ++kc) {
            const _Float16* wbase = wp + ((size_t)(batch * 3 + kh) * 4 + kc) * 12288 + wrow;
            const _Float16* xbase = sX + (size_t)(kh * 16 + kc * 4) * 528;   // 66*8
#pragma unroll
            for (int ks = 0; ks < 6; ++ks) {
                const int kw = ks >> 1, kk = ks & 1;
                h8 af, bf0, bf1;
                af  = *(const h8*)&wbase[(size_t)((kw * 4 + kk * 2) * 128) * 8];
                bf0 = *(const h8*)&xbase[((kk * 2 + lhi) * 66 + l31 + kw) * 8];
                bf1 = *(const h8*)&xbase[((kk * 2 + lhi) * 66 + 32 + l31 + kw) * 8];
                __builtin_amdgcn_s_setprio(1);
                acc[0] = MFMA32(af, bf0, acc[0], 0, 0, 0);
                acc[1] = MFMA32(af, bf1, acc[1], 0, 0, 0);
                __builtin_amdgcn_s_setprio(0);
            }
        }
    }

    // ---- epilogue: residual add + store ----
#pragma unroll
    for (int nt = 0; nt < 2; ++nt)
#pragma unroll
        for (int rg = 0; rg < 16; ++rg) {
            int co = wv * 32 + (rg & 3) + 8 * (rg >> 2) + 4 * lhi;
            int x  = nt * 32 + l31;
            size_t o = ((size_t)(batch * 128 + co) * 64 + h) * 64 + x;
            out[o] = X[o] + acc[nt][rg];
        }
}

extern "C" void kernel_launch(void* const* d_in, const int* in_sizes, int n_in,
                              void* d_out, int out_size, void* d_ws, size_t ws_size,
                              hipStream_t stream) {
    const float* inp = (const float*)d_in[0];
    const float* wgt = (const float*)d_in[1];
    float* out = (float*)d_out;
    _Float16* wpk = (_Float16*)d_ws;    // 16*3*4*12288 fp16 = 4.72 MB

    w_prepass<<<256, 256, 0, stream>>>(wgt, wpk);
    conv_main<<<1024, 256, 0, stream>>>(inp, wpk, out);
}